// Round 1
// baseline (35.060 us; speedup 1.0000x reference)
//
#include <hip/hip_runtime.h>

// Problem constants (from reference):
//   x:    [B=64, C=3, H=384, W=384] float32
//   mask: [B, Wg=24, Hg=24] float32, keep patch iff mask >= 0.5
//   out[b,c,h,w] = x[b,c,h,w] * (mask[b, w/16, h/16] >= 0.5)
constexpr int PATCH = 16;
constexpr int B = 64, C = 3, H = 384, W = 384;
constexpr int Hg = H / PATCH, Wg = W / PATCH;
constexpr float P_OCCLUDE = 0.5f;
constexpr int N_ELEM = B * C * H * W;      // 28,311,552
constexpr int N4 = N_ELEM / 4;             // 7,077,888 float4s

__global__ void __launch_bounds__(256)
occlude_kernel(const float4* __restrict__ x,
               const float*  __restrict__ mask,
               float4* __restrict__ out) {
    int i = blockIdx.x * blockDim.x + threadIdx.x;
    if (i >= N4) return;

    int e = i * 4;                 // first element index of this float4
    // Decompose e -> (b, c, h, w). w%4 == 0 so all 4 elems share w/16.
    int w  = e % W;
    int t  = e / W;                // = ((b*C) + c) * H + h
    int h  = t % H;
    int bc = t / H;                // = b*C + c
    int b  = bc / C;

    int wg = w >> 4;               // w / PATCH
    int hg = h >> 4;               // h / PATCH

    float m = mask[(b * Wg + wg) * Hg + hg];
    float4 v = x[i];
    if (m < P_OCCLUDE) {
        v.x = 0.f; v.y = 0.f; v.z = 0.f; v.w = 0.f;
    }
    out[i] = v;
}

extern "C" void kernel_launch(void* const* d_in, const int* in_sizes, int n_in,
                              void* d_out, int out_size, void* d_ws, size_t ws_size,
                              hipStream_t stream) {
    const float4* x    = (const float4*)d_in[0];
    const float*  mask = (const float*)d_in[1];
    float4* out = (float4*)d_out;

    constexpr int BLOCK = 256;
    int grid = (N4 + BLOCK - 1) / BLOCK;   // 27,648 blocks
    occlude_kernel<<<grid, BLOCK, 0, stream>>>(x, mask, out);
}